// Round 14
// baseline (341.894 us; speedup 1.0000x reference)
//
#include <hip/hip_runtime.h>
#include <hip/hip_bf16.h>
#include <stdint.h>

// ---------------------------------------------------------------------------
// Problem constants
// ---------------------------------------------------------------------------
#define NCLS   6
#define NATOMS 5
#define B_     64
#define P_     196
#define D_     768
#define H_     3072
#define SEQ    (NCLS + P_)        // 202
#define NPATCH (B_ * P_)          // 12544
#define NPAIR  (B_ * NCLS)        // 384

typedef unsigned short ushort_t;
typedef __attribute__((ext_vector_type(8))) short  bf16x8;
typedef __attribute__((ext_vector_type(4))) float  f32x4;

// ---------------------------------------------------------------------------
// Helpers
// ---------------------------------------------------------------------------
// fast tanh-form GELU (max abs err ~1e-3; threshold budget 3.98e-2)
__device__ __forceinline__ float gelu_fast(float x) {
    float x2 = x * x;
    float y  = x * (1.59576912f + 0.07135482f * x2);
    float e  = __expf(y);
    return x * e / (e + 1.0f);
}

__device__ __forceinline__ ushort_t f2bf(float f) {
    uint32_t u = __builtin_bit_cast(uint32_t, f);
    u = (u + 0x7fffu + ((u >> 16) & 1u)) >> 16;
    return (ushort_t)u;
}

__device__ __forceinline__ void gload16(const ushort_t* g, ushort_t* l) {
    __builtin_amdgcn_global_load_lds(
        (const __attribute__((address_space(1))) uint32_t*)g,
        (__attribute__((address_space(3))) uint32_t*)l,
        16, 0, 0);
}

// ---------------------------------------------------------------------------
// prep kernel: w1/w2 fp32->bf16, x split, AND gate — one launch.
// (aiw/aow are NOT converted: the cls GEMMs stage them from fp32 directly.)
// ---------------------------------------------------------------------------
#define CVT_B1   (H_ * D_ / 1024)             // w1:  2304 blocks
#define CVT_B2   (CVT_B1 + D_ * H_ / 1024)    // +w2: 4608
#define PREP_XE  (CVT_B2 + B_ * SEQ * D_ / 1024)  // +x: 14304
#define PREP_NB  (PREP_XE + NPAIR / 4)        // +gate (4 pairs/block): 14400

__global__ void prep_kernel(const float* __restrict__ w1, ushort_t* __restrict__ o1,
                            const float* __restrict__ w2, ushort_t* __restrict__ o2,
                            const float* __restrict__ x, ushort_t* __restrict__ xp,
                            ushort_t* __restrict__ cls,
                            const float* __restrict__ gd,
                            int* __restrict__ srcA, int* __restrict__ dstA,
                            float* __restrict__ wgtA) {
    int bid = blockIdx.x;
    if (bid < CVT_B2) {
        const float* src; ushort_t* dst; int i;
        if (bid < CVT_B1) { src = w1; dst = o1; i = bid * 1024; }
        else              { src = w2; dst = o2; i = (bid - CVT_B1) * 1024; }
        i += threadIdx.x * 4;
        float4 v = *(const float4*)(src + i);
        ushort4 o;
        o.x = f2bf(v.x); o.y = f2bf(v.y); o.z = f2bf(v.z); o.w = f2bf(v.w);
        *(ushort4*)(dst + i) = o;
    } else if (bid < PREP_XE) {
        int i = (bid - CVT_B2) * 1024 + threadIdx.x * 4;
        int row = i / D_;
        int col = i - row * D_;
        int b = row / SEQ, s = row - b * SEQ;
        float4 v = *(const float4*)(x + i);
        ushort4 o;
        o.x = f2bf(v.x); o.y = f2bf(v.y); o.z = f2bf(v.z); o.w = f2bf(v.w);
        if (s < NCLS) {
            *(ushort4*)(cls + (size_t)(b * NCLS + s) * D_ + col) = o;
        } else {
            *(ushort4*)(xp + (size_t)(b * P_ + (s - NCLS)) * D_ + col) = o;
        }
    } else {
        // gate: one wave per (b, n) pair
        int r = (bid - PREP_XE) * 4 + (threadIdx.x >> 6);
        int lane = threadIdx.x & 63;
        int b = r / NCLS, n = r - b * NCLS;
        const float* xr = x + (size_t)(b * SEQ + n) * D_;
        const float* g  = gd + (size_t)n * D_;
        float s = 0.f;
        for (int k = lane; k < D_; k += 64) s += xr[k] * g[k];
        #pragma unroll
        for (int off = 32; off > 0; off >>= 1) s += __shfl_down(s, off, 64);
        if (lane == 0) {
            float logit = s;
            bool left = (logit >= 0.f);
            float p = 1.f / (1.f + expf(-logit));
            float w = left ? p : (1.f - p);
            const int LK[NCLS] = {3, 4, 8, 9, 13, 14};
            const int RK[NCLS] = {15, 20, 16, 21, 17, 22};
            int key = left ? LK[n] : RK[n];
            srcA[r] = key / NATOMS;
            dstA[r] = key % NATOMS;
            wgtA[r] = w;
        }
    }
}

// ===========================================================================
// Shared GEMM building blocks
// ===========================================================================
// stage a [ROWS x 32] bf16 tile; inverse-swizzled global source, linear dest.
template <int ROWS, int NT>
__device__ __forceinline__ void stage_t32(const ushort_t* __restrict__ gpanel, int K,
                                          int kbase, ushort_t* lds, int tid) {
    constexpr int LOADS = ROWS * 4 / NT;
    static_assert(LOADS * NT == ROWS * 4, "stage divisibility");
    #pragma unroll
    for (int l = 0; l < LOADS; ++l) {
        int c = l * NT + tid;
        int row = c >> 2;
        int col = ((c & 3) ^ ((row >> 1) & 3)) << 3;
        gload16(gpanel + (size_t)row * K + kbase + col, lds + ((size_t)c << 3));
    }
}

#define BAR     asm volatile("s_barrier" ::: "memory")
#define VMW(N)  asm volatile("s_waitcnt vmcnt(" #N ")" ::: "memory")
#define VMW_C(VAL) do { \
    if constexpr ((VAL) == 4) { VMW(4); } else { VMW(8); } } while (0)

// ===========================================================================
// gemm2s: r9-proven BK=64 2-phase counted-vmcnt GEMM (both patch GEMMs).
// 128x128 tile, 8 waves (2M x 4N), 64 KB LDS -> 2 blk/CU.  Per K-tile:
// stage next tile -> VMW(4) (next tile stays in flight; drains current) ->
// barrier -> 32-MFMA/wave cluster -> barrier.  L2 cohorts 7m x 3n;
// swizzle slot^=(row>>1)&3 (0 bank conflicts).  Proven 105us @ K=768.
// Config sweep r9-r13 ({8w,4w}x{BK32,BK64}x{2,3}blk) confirms this is the
// 2-phase structure's minimum; deep-pipeline 256^2 is grid-tail-handicapped
// at our sizes (588/147 blocks @ 1 blk/CU).
// ===========================================================================
#define STAGE64T(T, DB) \
    stage_t32<BM, NT>(Ab, K, ((T) << 6),      &LA[DB][0][0], tid); \
    stage_t32<BN, NT>(Bb, K, ((T) << 6),      &LB[DB][0][0], tid); \
    stage_t32<BM, NT>(Ab, K, ((T) << 6) + 32, &LA[DB][1][0], tid); \
    stage_t32<BN, NT>(Bb, K, ((T) << 6) + 32, &LB[DB][1][0], tid);

#define COMPUTE64(DB) do { \
    __builtin_amdgcn_s_setprio(1); \
    _Pragma("unroll") \
    for (int ks = 0; ks < 2; ++ks) { \
        bf16x8 bfr[FN]; \
        _Pragma("unroll") \
        for (int f = 0; f < FN; ++f) \
            bfr[f] = *(const bf16x8*)(&LB[DB][ks][bbase + f * 512]); \
        _Pragma("unroll") \
        for (int mh = 0; mh < 2; ++mh) { \
            bf16x8 afr[FMH]; \
            _Pragma("unroll") \
            for (int f = 0; f < FMH; ++f) \
                afr[f] = *(const bf16x8*)(&LA[DB][ks][abase + mh * MH_OFF + f * 512]); \
            _Pragma("unroll") \
            for (int mi = 0; mi < FMH; ++mi) \
                _Pragma("unroll") \
                for (int ni = 0; ni < FN; ++ni) \
                    acc[mh * FMH + mi][ni] = __builtin_amdgcn_mfma_f32_16x16x32_bf16( \
                        afr[mi], bfr[ni], acc[mh * FMH + mi][ni], 0, 0, 0); \
        } \
    } \
    __builtin_amdgcn_s_setprio(0); \
    __builtin_amdgcn_sched_barrier(0); \
} while (0)

// MODE 0: H1 = bf16(gelu(acc + bias[n]))          (patch layer 1)
// MODE 1: out[(b*SEQ+NCLS+p)*D_+n] = acc+bias[n]  (patch layer 2)
template <int MODE, int BM, int BN, int WM, int WN, int MINW>
__global__ __launch_bounds__(WM * WN * 64, MINW)
void gemm2s(const ushort_t* __restrict__ A, const ushort_t* __restrict__ Bm,
            int N, int K, int grid_m, int grid_n,
            const float* __restrict__ bias,
            float* __restrict__ outF, ushort_t* __restrict__ outB) {
    constexpr int NT   = WM * WN * 64;
    constexpr int FMH  = BM / (32 * WM);
    constexpr int FN   = BN / (16 * WN);
    constexpr int MH_OFF = (BM / WM / 2) * 32;
    constexpr int VMWN = 8 * (BM + BN) / NT;

    __shared__ __align__(16) ushort_t LA[2][2][BM * 32];
    __shared__ __align__(16) ushort_t LB[2][2][BN * 32];

    // bijective XCD-chunk swizzle (m204) + L2 cohort decode (7m x 3n)
    const int nwg = gridDim.x;
    int bid = blockIdx.x;
    int q = nwg >> 3, r = nwg & 7;
    int xcd = bid & 7, slot = bid >> 3;
    int wg = (xcd < r ? xcd * (q + 1) : r * (q + 1) + (xcd - r) * q) + slot;
    int per_col = (grid_m / 7) * 21;
    int gn = wg / per_col;  int r1 = wg - gn * per_col;
    int gm = r1 / 21;       int ii = r1 - gm * 21;
    int tile_m = gm * 7 + ii / 3;
    int tile_n = gn * 3 + (ii - (ii / 3) * 3);

    const ushort_t* Ab = A  + (size_t)tile_m * BM * K;
    const ushort_t* Bb = Bm + (size_t)tile_n * BN * K;

    const int tid  = threadIdx.x;
    const int lane = tid & 63;
    const int wave = tid >> 6;
    const int wr = wave / WN;
    const int wc = wave % WN;

    const int frow = lane & 15;
    const int fsl  = lane >> 4;
    const int rbase = frow * 32 + ((fsl ^ ((frow >> 1) & 3)) << 3);
    const int abase = wr * ((BM / WM) * 32) + rbase;
    const int bbase = wc * ((BN / WN) * 32) + rbase;

    f32x4 acc[2 * FMH][FN];
    #pragma unroll
    for (int i = 0; i < 2 * FMH; i++)
        #pragma unroll
        for (int j = 0; j < FN; j++)
            acc[i][j] = (f32x4){0.f, 0.f, 0.f, 0.f};

    const int nkt = K >> 6;

    STAGE64T(0, 0)
    for (int tb = 0; tb < (nkt >> 1) - 1; ++tb) {
        STAGE64T(2 * tb + 1, 1)
        VMW_C(VMWN); BAR;
        COMPUTE64(0);
        BAR;
        STAGE64T(2 * tb + 2, 0)
        VMW_C(VMWN); BAR;
        COMPUTE64(1);
        BAR;
    }
    STAGE64T(nkt - 1, 1)
    VMW_C(VMWN); BAR;
    COMPUTE64(0);
    BAR;
    VMW(0); BAR;
    COMPUTE64(1);

    // epilogue: C/D layout col = lane&15, row = (lane>>4)*4 + reg
    const int fq = lane >> 4;
    #pragma unroll
    for (int mi = 0; mi < 2 * FMH; mi++) {
        #pragma unroll
        for (int ni = 0; ni < FN; ni++) {
            int n = tile_n * BN + wc * (BN / WN) + ni * 16 + frow;
            float bn = bias[n];
            #pragma unroll
            for (int rr = 0; rr < 4; rr++) {
                int m = tile_m * BM + wr * (BM / WM) + mi * 16 + fq * 4 + rr;
                float v = acc[mi][ni][rr];
                if constexpr (MODE == 0) {
                    outB[(size_t)m * N + n] = f2bf(gelu_fast(v + bn));
                } else {
                    int b = m / P_, p = m - b * P_;
                    outF[(size_t)(b * SEQ + NCLS + p) * D_ + n] = v + bn;
                }
            }
        }
    }
}

// ---------------------------------------------------------------------------
// cls-path GEMM, B staged DIRECTLY FROM FP32 (reg-stage + inline f2bf):
// removes the aiw/aow conversion passes (94 MB read + 47 MB write) from prep.
// Latency-regime kernels; B-panels are L2/L3-resident across the z-sweep.
// A (bf16) keeps async gload_lds staging; 2-phase double-buffer as before.
// ---------------------------------------------------------------------------
template <int ROWS, int NT>
__device__ __forceinline__ void stage64(const ushort_t* __restrict__ gbase, int K,
                                        int k0, ushort_t* lds, int tid) {
    constexpr int LOADS = ROWS * 64 * 2 / (NT * 16);
    #pragma unroll
    for (int l = 0; l < LOADS; ++l) {
        int c = l * NT + tid;
        gload16(gbase + (size_t)(c >> 3) * K + k0 + ((c & 7) << 3),
                lds + (size_t)c * 8);
    }
}

// stage a [ROWS x 64] tile from an fp32 source: chunk c -> row c>>3,
// col (c&7)*8 (8 elems), cvt to bf16, one ds_write_b128.  Same LDS layout
// as stage64 -> read side (compute64c) unchanged.
template <int ROWS, int NT>
__device__ __forceinline__ void stageB_f32(const float* __restrict__ gbase, int K,
                                           int k0, ushort_t* lds, int tid) {
    constexpr int LOADS = ROWS * 8 / NT;
    #pragma unroll
    for (int l = 0; l < LOADS; ++l) {
        int c = l * NT + tid;
        const float* src = gbase + (size_t)(c >> 3) * K + k0 + ((c & 7) << 3);
        float4 v0 = *(const float4*)(src);
        float4 v1 = *(const float4*)(src + 4);
        bf16x8 s;
        s[0] = (short)f2bf(v0.x); s[1] = (short)f2bf(v0.y);
        s[2] = (short)f2bf(v0.z); s[3] = (short)f2bf(v0.w);
        s[4] = (short)f2bf(v1.x); s[5] = (short)f2bf(v1.y);
        s[6] = (short)f2bf(v1.z); s[7] = (short)f2bf(v1.w);
        *(bf16x8*)(lds + (size_t)c * 8) = s;
    }
}

template <int FM, int FN>
__device__ __forceinline__ void compute64c(const ushort_t* sA, const ushort_t* sB,
                                           int arow0, int brow0, int lane,
                                           f32x4 (&acc)[FM][FN]) {
    const int frow = lane & 15;
    const int fcol = (lane >> 4) * 8;
    #pragma unroll
    for (int ks = 0; ks < 2; ++ks) {
        bf16x8 af[FM], bfv[FN];
        #pragma unroll
        for (int mi = 0; mi < FM; ++mi)
            af[mi] = *(const bf16x8*)(sA + (size_t)(arow0 + mi * 16 + frow) * 64 + ks * 32 + fcol);
        #pragma unroll
        for (int ni = 0; ni < FN; ++ni)
            bfv[ni] = *(const bf16x8*)(sB + (size_t)(brow0 + ni * 16 + frow) * 64 + ks * 32 + fcol);
        #pragma unroll
        for (int mi = 0; mi < FM; ++mi)
            #pragma unroll
            for (int ni = 0; ni < FN; ++ni)
                acc[mi][ni] = __builtin_amdgcn_mfma_f32_16x16x32_bf16(
                    af[mi], bfv[ni], acc[mi][ni], 0, 0, 0);
    }
}

// MODE 2: if src[m]==atom: HID = bf16(gelu(acc + bias[atom*H_+n]))
// MODE 3: if dst[m]==atom: out[(b*SEQ+nn)*D_+n] = (acc + bias[atom*D_+n])*wgt[m]
template <int MODE, int BMc, int BNc, int WM, int WN>
__global__ __launch_bounds__(WM * WN * 64, 2)
void gemm2p(const ushort_t* __restrict__ A,
            const float* __restrict__ Bm,          // fp32 atom weights
            int N, int K, int grid_n,
            const float* __restrict__ bias,
            float* __restrict__ outF,
            ushort_t* __restrict__ outB,
            const int* __restrict__ selIdx,
            const float* __restrict__ wgt) {
    constexpr int NT = WM * WN * 64;
    constexpr int FM = BMc / WM / 16;
    constexpr int FN = BNc / WN / 16;

    __shared__ __align__(16) ushort_t A0[BMc * 64], A1[BMc * 64];
    __shared__ __align__(16) ushort_t B0[BNc * 64], B1[BNc * 64];

    const int nwg = gridDim.x;
    int bid = blockIdx.x;
    int q = nwg >> 3, r = nwg & 7;
    int xcd = bid & 7, slot = bid >> 3;
    int wg = (xcd < r ? xcd * (q + 1) : r * (q + 1) + (xcd - r) * q) + slot;
    int tile_m = wg / grid_n;
    int tile_n = wg - tile_m * grid_n;
    const int atom = blockIdx.z;

    const ushort_t* Ab = A  + (size_t)tile_m * BMc * K;
    const float*    Bb = Bm + ((size_t)atom * N + (size_t)tile_n * BNc) * K;

    const int tid  = threadIdx.x;
    const int lane = tid & 63;
    const int wave = tid >> 6;
    const int arow0 = (wave / WN) * (BMc / WM);
    const int brow0 = (wave % WN) * (BNc / WN);

    f32x4 acc[FM][FN];
    #pragma unroll
    for (int i = 0; i < FM; i++)
        #pragma unroll
        for (int j = 0; j < FN; j++)
            acc[i][j] = (f32x4){0.f, 0.f, 0.f, 0.f};

    const int nkt = K >> 6;

    stage64<BMc, NT>(Ab, K, 0, A0, tid);
    stageB_f32<BNc, NT>(Bb, K, 0, B0, tid);
    asm volatile("s_waitcnt vmcnt(0)" ::: "memory");
    __syncthreads();

    for (int t = 0; t < nkt; t += 2) {
        stage64<BMc, NT>(Ab, K, (t + 1) << 6, A1, tid);
        stageB_f32<BNc, NT>(Bb, K, (t + 1) << 6, B1, tid);
        compute64c<FM, FN>(A0, B0, arow0, brow0, lane, acc);
        asm volatile("s_waitcnt vmcnt(0)" ::: "memory");
        __syncthreads();
        if (t + 2 < nkt) {
            stage64<BMc, NT>(Ab, K, (t + 2) << 6, A0, tid);
            stageB_f32<BNc, NT>(Bb, K, (t + 2) << 6, B0, tid);
        }
        compute64c<FM, FN>(A1, B1, arow0, brow0, lane, acc);
        asm volatile("s_waitcnt vmcnt(0)" ::: "memory");
        __syncthreads();
    }

    const int frow = lane & 15;
    const int fq   = lane >> 4;
    #pragma unroll
    for (int mi = 0; mi < FM; mi++) {
        #pragma unroll
        for (int ni = 0; ni < FN; ni++) {
            int n = tile_n * BNc + brow0 + ni * 16 + frow;
            float bn;
            if constexpr (MODE == 2) bn = bias[atom * H_ + n];
            else                     bn = bias[atom * D_ + n];
            #pragma unroll
            for (int rr = 0; rr < 4; rr++) {
                int m = tile_m * BMc + arow0 + mi * 16 + fq * 4 + rr;
                float v = acc[mi][ni][rr];
                if constexpr (MODE == 2) {
                    if (selIdx[m] == atom)
                        outB[(size_t)m * N + n] = f2bf(gelu_fast(v + bn));
                } else { // MODE 3
                    if (selIdx[m] == atom) {
                        int b = m / NCLS, nn = m - b * NCLS;
                        outF[(size_t)(b * SEQ + nn) * D_ + n] = (v + bn) * wgt[m];
                    }
                }
            }
        }
    }
}

// ---------------------------------------------------------------------------
// Launch
// ---------------------------------------------------------------------------
extern "C" void kernel_launch(void* const* d_in, const int* in_sizes, int n_in,
                              void* d_out, int out_size, void* d_ws, size_t ws_size,
                              hipStream_t stream) {
    const float* x   = (const float*)d_in[0];
    const float* w1  = (const float*)d_in[1];
    const float* b1  = (const float*)d_in[2];
    const float* w2  = (const float*)d_in[3];
    const float* b2  = (const float*)d_in[4];
    const float* gd  = (const float*)d_in[5];
    const float* aiw = (const float*)d_in[6];
    const float* aib = (const float*)d_in[7];
    const float* aow = (const float*)d_in[8];
    const float* aob = (const float*)d_in[9];
    float* out = (float*)d_out;

    char* ws = (char*)d_ws;
    ushort_t* Xp   = (ushort_t*)ws; ws += (size_t)NPATCH * D_ * 2;
    ushort_t* W1b  = (ushort_t*)ws; ws += (size_t)H_ * D_ * 2;
    ushort_t* W2b  = (ushort_t*)ws; ws += (size_t)D_ * H_ * 2;
    ushort_t* H1   = (ushort_t*)ws; ws += (size_t)NPATCH * H_ * 2;
    ushort_t* CLSb = (ushort_t*)ws; ws += (size_t)NPAIR * D_ * 2;
    ushort_t* HID  = (ushort_t*)ws; ws += (size_t)NPAIR * H_ * 2;
    int*   SRC = (int*)ws;   ws += NPAIR * 4;
    int*   DST = (int*)ws;   ws += NPAIR * 4;
    float* WGT = (float*)ws; ws += NPAIR * 4;

    // prep: w1/w2 conversion + x split + gate, one launch
    prep_kernel<<<PREP_NB, 256, 0, stream>>>(w1, W1b, w2, W2b, x, Xp, CLSb,
                                             gd, SRC, DST, WGT);

    // patch MLP: r9-proven config for both GEMMs
    // (128x128 / BK=64 / 8 waves / 64KB LDS -> 2 blk/CU, counted VMW(4))
    gemm2s<0, 128, 128, 2, 4, 4><<<dim3(2352, 1, 1), 512, 0, stream>>>(
        Xp, W1b, H_, D_, 98, 24, b1, nullptr, H1);
    gemm2s<1, 128, 128, 2, 4, 4><<<dim3(588, 1, 1), 512, 0, stream>>>(
        H1, W2b, D_, H_, 98, 6, b2, out, nullptr);

    // cls path: dense all-atom GEMMs, B staged directly from fp32
    gemm2p<2, 64, 128, 1, 2><<<dim3(NPAIR / 64 * (H_ / 128), 1, NATOMS), 128, 0, stream>>>(
        CLSb, aiw, H_, D_, H_ / 128, aib, nullptr, HID, SRC, nullptr);
    gemm2p<3, 64, 128, 1, 2><<<dim3(NPAIR / 64 * (D_ / 128), 1, NATOMS), 128, 0, stream>>>(
        HID, aow, D_, H_, D_ / 128, aob, out, nullptr, DST, WGT);
}

// Round 15
// 292.754 us; speedup vs baseline: 1.1679x; 1.1679x over previous
//
#include <hip/hip_runtime.h>
#include <hip/hip_bf16.h>
#include <stdint.h>

// ---------------------------------------------------------------------------
// Problem constants
// ---------------------------------------------------------------------------
#define NCLS   6
#define NATOMS 5
#define B_     64
#define P_     196
#define D_     768
#define H_     3072
#define SEQ    (NCLS + P_)        // 202
#define NPATCH (B_ * P_)          // 12544
#define NPAIR  (B_ * NCLS)        // 384

typedef unsigned short ushort_t;
typedef __attribute__((ext_vector_type(8))) short  bf16x8;
typedef __attribute__((ext_vector_type(4))) float  f32x4;

// ---------------------------------------------------------------------------
// Helpers
// ---------------------------------------------------------------------------
// fast tanh-form GELU (max abs err ~1e-3; threshold budget 3.98e-2)
__device__ __forceinline__ float gelu_fast(float x) {
    float x2 = x * x;
    float y  = x * (1.59576912f + 0.07135482f * x2);
    float e  = __expf(y);
    return x * e / (e + 1.0f);
}

__device__ __forceinline__ ushort_t f2bf(float f) {
    uint32_t u = __builtin_bit_cast(uint32_t, f);
    u = (u + 0x7fffu + ((u >> 16) & 1u)) >> 16;
    return (ushort_t)u;
}

__device__ __forceinline__ void gload16(const ushort_t* g, ushort_t* l) {
    __builtin_amdgcn_global_load_lds(
        (const __attribute__((address_space(1))) uint32_t*)g,
        (__attribute__((address_space(3))) uint32_t*)l,
        16, 0, 0);
}

// ---------------------------------------------------------------------------
// prep kernel: all fp32->bf16 conversions (w1,w2,aiw,aow) + x split + gate,
// ONE launch.  (r14 lesson: cls GEMMs MUST consume pre-converted bf16 —
// fp32 reg-staging broke the async pipeline and tripled HBM traffic.)
// ---------------------------------------------------------------------------
#define CVT_B1   (H_ * D_ / 1024)                     // w1:   2304
#define CVT_B2   (CVT_B1 + D_ * H_ / 1024)            // +w2:  4608
#define CVT_B3   (CVT_B2 + NATOMS * H_ * D_ / 1024)   // +aiw: 16128
#define CVT_B4   (CVT_B3 + NATOMS * D_ * H_ / 1024)   // +aow: 27648
#define PREP_XE  (CVT_B4 + B_ * SEQ * D_ / 1024)      // +x:   37344
#define PREP_NB  (PREP_XE + NPAIR / 4)                // +gate: 37440

__global__ void prep_kernel(const float* __restrict__ w1, ushort_t* __restrict__ o1,
                            const float* __restrict__ w2, ushort_t* __restrict__ o2,
                            const float* __restrict__ aiw, ushort_t* __restrict__ o3,
                            const float* __restrict__ aow, ushort_t* __restrict__ o4,
                            const float* __restrict__ x, ushort_t* __restrict__ xp,
                            ushort_t* __restrict__ cls,
                            const float* __restrict__ gd,
                            int* __restrict__ srcA, int* __restrict__ dstA,
                            float* __restrict__ wgtA) {
    int bid = blockIdx.x;
    if (bid < CVT_B4) {
        const float* src; ushort_t* dst; int i;
        if (bid < CVT_B1)      { src = w1;  dst = o1; i = bid * 1024; }
        else if (bid < CVT_B2) { src = w2;  dst = o2; i = (bid - CVT_B1) * 1024; }
        else if (bid < CVT_B3) { src = aiw; dst = o3; i = (bid - CVT_B2) * 1024; }
        else                   { src = aow; dst = o4; i = (bid - CVT_B3) * 1024; }
        i += threadIdx.x * 4;
        float4 v = *(const float4*)(src + i);
        ushort4 o;
        o.x = f2bf(v.x); o.y = f2bf(v.y); o.z = f2bf(v.z); o.w = f2bf(v.w);
        *(ushort4*)(dst + i) = o;
    } else if (bid < PREP_XE) {
        int i = (bid - CVT_B4) * 1024 + threadIdx.x * 4;
        int row = i / D_;
        int col = i - row * D_;
        int b = row / SEQ, s = row - b * SEQ;
        float4 v = *(const float4*)(x + i);
        ushort4 o;
        o.x = f2bf(v.x); o.y = f2bf(v.y); o.z = f2bf(v.z); o.w = f2bf(v.w);
        if (s < NCLS) {
            *(ushort4*)(cls + (size_t)(b * NCLS + s) * D_ + col) = o;
        } else {
            *(ushort4*)(xp + (size_t)(b * P_ + (s - NCLS)) * D_ + col) = o;
        }
    } else {
        // gate: one wave per (b, n) pair
        int r = (bid - PREP_XE) * 4 + (threadIdx.x >> 6);
        int lane = threadIdx.x & 63;
        int b = r / NCLS, n = r - b * NCLS;
        const float* xr = x + (size_t)(b * SEQ + n) * D_;
        const float* g  = gd + (size_t)n * D_;
        float s = 0.f;
        for (int k = lane; k < D_; k += 64) s += xr[k] * g[k];
        #pragma unroll
        for (int off = 32; off > 0; off >>= 1) s += __shfl_down(s, off, 64);
        if (lane == 0) {
            float logit = s;
            bool left = (logit >= 0.f);
            float p = 1.f / (1.f + expf(-logit));
            float w = left ? p : (1.f - p);
            const int LK[NCLS] = {3, 4, 8, 9, 13, 14};
            const int RK[NCLS] = {15, 20, 16, 21, 17, 22};
            int key = left ? LK[n] : RK[n];
            srcA[r] = key / NATOMS;
            dstA[r] = key % NATOMS;
            wgtA[r] = w;
        }
    }
}

// ===========================================================================
// Shared GEMM building blocks
// ===========================================================================
// stage a [ROWS x 32] bf16 tile; inverse-swizzled global source, linear dest.
template <int ROWS, int NT>
__device__ __forceinline__ void stage_t32(const ushort_t* __restrict__ gpanel, int K,
                                          int kbase, ushort_t* lds, int tid) {
    constexpr int LOADS = ROWS * 4 / NT;
    static_assert(LOADS * NT == ROWS * 4, "stage divisibility");
    #pragma unroll
    for (int l = 0; l < LOADS; ++l) {
        int c = l * NT + tid;
        int row = c >> 2;
        int col = ((c & 3) ^ ((row >> 1) & 3)) << 3;
        gload16(gpanel + (size_t)row * K + kbase + col, lds + ((size_t)c << 3));
    }
}

#define BAR     asm volatile("s_barrier" ::: "memory")
#define VMW(N)  asm volatile("s_waitcnt vmcnt(" #N ")" ::: "memory")
#define VMW_C(VAL) do { \
    if constexpr ((VAL) == 4) { VMW(4); } else { VMW(8); } } while (0)

// ===========================================================================
// gemm2s: r9-proven BK=64 2-phase counted-vmcnt GEMM (both patch GEMMs).
// 128x128 tile, 8 waves (2M x 4N), 64 KB LDS -> 2 blk/CU.  Per K-tile:
// stage next tile -> VMW(4) (next tile stays in flight; drains current) ->
// barrier -> 32-MFMA/wave cluster -> barrier.  L2 cohorts 7m x 3n;
// swizzle slot^=(row>>1)&3 (0 bank conflicts).  105us @ 4096x3072x768.
// Config sweep r9-r13 ({8w,4w}x{BK32,BK64}x{2,3}blk) says this is the
// 2-phase minimum; deep-pipeline 256^2 is grid-tail-handicapped here.
// ===========================================================================
#define STAGE64T(T, DB) \
    stage_t32<BM, NT>(Ab, K, ((T) << 6),      &LA[DB][0][0], tid); \
    stage_t32<BN, NT>(Bb, K, ((T) << 6),      &LB[DB][0][0], tid); \
    stage_t32<BM, NT>(Ab, K, ((T) << 6) + 32, &LA[DB][1][0], tid); \
    stage_t32<BN, NT>(Bb, K, ((T) << 6) + 32, &LB[DB][1][0], tid);

#define COMPUTE64(DB) do { \
    __builtin_amdgcn_s_setprio(1); \
    _Pragma("unroll") \
    for (int ks = 0; ks < 2; ++ks) { \
        bf16x8 bfr[FN]; \
        _Pragma("unroll") \
        for (int f = 0; f < FN; ++f) \
            bfr[f] = *(const bf16x8*)(&LB[DB][ks][bbase + f * 512]); \
        _Pragma("unroll") \
        for (int mh = 0; mh < 2; ++mh) { \
            bf16x8 afr[FMH]; \
            _Pragma("unroll") \
            for (int f = 0; f < FMH; ++f) \
                afr[f] = *(const bf16x8*)(&LA[DB][ks][abase + mh * MH_OFF + f * 512]); \
            _Pragma("unroll") \
            for (int mi = 0; mi < FMH; ++mi) \
                _Pragma("unroll") \
                for (int ni = 0; ni < FN; ++ni) \
                    acc[mh * FMH + mi][ni] = __builtin_amdgcn_mfma_f32_16x16x32_bf16( \
                        afr[mi], bfr[ni], acc[mh * FMH + mi][ni], 0, 0, 0); \
        } \
    } \
    __builtin_amdgcn_s_setprio(0); \
    __builtin_amdgcn_sched_barrier(0); \
} while (0)

// MODE 0: H1 = bf16(gelu(acc + bias[n]))          (patch layer 1)
// MODE 1: out[(b*SEQ+NCLS+p)*D_+n] = acc+bias[n]  (patch layer 2)
template <int MODE, int BM, int BN, int WM, int WN, int MINW>
__global__ __launch_bounds__(WM * WN * 64, MINW)
void gemm2s(const ushort_t* __restrict__ A, const ushort_t* __restrict__ Bm,
            int N, int K, int grid_m, int grid_n,
            const float* __restrict__ bias,
            float* __restrict__ outF, ushort_t* __restrict__ outB) {
    constexpr int NT   = WM * WN * 64;
    constexpr int FMH  = BM / (32 * WM);
    constexpr int FN   = BN / (16 * WN);
    constexpr int MH_OFF = (BM / WM / 2) * 32;
    constexpr int VMWN = 8 * (BM + BN) / NT;

    __shared__ __align__(16) ushort_t LA[2][2][BM * 32];
    __shared__ __align__(16) ushort_t LB[2][2][BN * 32];

    // bijective XCD-chunk swizzle (m204) + L2 cohort decode (7m x 3n)
    const int nwg = gridDim.x;
    int bid = blockIdx.x;
    int q = nwg >> 3, r = nwg & 7;
    int xcd = bid & 7, slot = bid >> 3;
    int wg = (xcd < r ? xcd * (q + 1) : r * (q + 1) + (xcd - r) * q) + slot;
    int per_col = (grid_m / 7) * 21;
    int gn = wg / per_col;  int r1 = wg - gn * per_col;
    int gm = r1 / 21;       int ii = r1 - gm * 21;
    int tile_m = gm * 7 + ii / 3;
    int tile_n = gn * 3 + (ii - (ii / 3) * 3);

    const ushort_t* Ab = A  + (size_t)tile_m * BM * K;
    const ushort_t* Bb = Bm + (size_t)tile_n * BN * K;

    const int tid  = threadIdx.x;
    const int lane = tid & 63;
    const int wave = tid >> 6;
    const int wr = wave / WN;
    const int wc = wave % WN;

    const int frow = lane & 15;
    const int fsl  = lane >> 4;
    const int rbase = frow * 32 + ((fsl ^ ((frow >> 1) & 3)) << 3);
    const int abase = wr * ((BM / WM) * 32) + rbase;
    const int bbase = wc * ((BN / WN) * 32) + rbase;

    f32x4 acc[2 * FMH][FN];
    #pragma unroll
    for (int i = 0; i < 2 * FMH; i++)
        #pragma unroll
        for (int j = 0; j < FN; j++)
            acc[i][j] = (f32x4){0.f, 0.f, 0.f, 0.f};

    const int nkt = K >> 6;

    STAGE64T(0, 0)
    for (int tb = 0; tb < (nkt >> 1) - 1; ++tb) {
        STAGE64T(2 * tb + 1, 1)
        VMW_C(VMWN); BAR;
        COMPUTE64(0);
        BAR;
        STAGE64T(2 * tb + 2, 0)
        VMW_C(VMWN); BAR;
        COMPUTE64(1);
        BAR;
    }
    STAGE64T(nkt - 1, 1)
    VMW_C(VMWN); BAR;
    COMPUTE64(0);
    BAR;
    VMW(0); BAR;
    COMPUTE64(1);

    // epilogue: C/D layout col = lane&15, row = (lane>>4)*4 + reg
    const int fq = lane >> 4;
    #pragma unroll
    for (int mi = 0; mi < 2 * FMH; mi++) {
        #pragma unroll
        for (int ni = 0; ni < FN; ni++) {
            int n = tile_n * BN + wc * (BN / WN) + ni * 16 + frow;
            float bn = bias[n];
            #pragma unroll
            for (int rr = 0; rr < 4; rr++) {
                int m = tile_m * BM + wr * (BM / WM) + mi * 16 + fq * 4 + rr;
                float v = acc[mi][ni][rr];
                if constexpr (MODE == 0) {
                    outB[(size_t)m * N + n] = f2bf(gelu_fast(v + bn));
                } else {
                    int b = m / P_, p = m - b * P_;
                    outF[(size_t)(b * SEQ + NCLS + p) * D_ + n] = v + bn;
                }
            }
        }
    }
}

// ---------------------------------------------------------------------------
// cls-path GEMM: r9-r13 proven 2-phase double-buffered, BK=64, bf16 inputs.
// (Underfilled-latency regime: dense 5-atom compute w/ masked scatter.)
// ---------------------------------------------------------------------------
template <int ROWS, int NT>
__device__ __forceinline__ void stage64(const ushort_t* __restrict__ gbase, int K,
                                        int k0, ushort_t* lds, int tid) {
    constexpr int LOADS = ROWS * 64 * 2 / (NT * 16);
    #pragma unroll
    for (int l = 0; l < LOADS; ++l) {
        int c = l * NT + tid;
        gload16(gbase + (size_t)(c >> 3) * K + k0 + ((c & 7) << 3),
                lds + (size_t)c * 8);
    }
}

template <int FM, int FN>
__device__ __forceinline__ void compute64c(const ushort_t* sA, const ushort_t* sB,
                                           int arow0, int brow0, int lane,
                                           f32x4 (&acc)[FM][FN]) {
    const int frow = lane & 15;
    const int fcol = (lane >> 4) * 8;
    #pragma unroll
    for (int ks = 0; ks < 2; ++ks) {
        bf16x8 af[FM], bfv[FN];
        #pragma unroll
        for (int mi = 0; mi < FM; ++mi)
            af[mi] = *(const bf16x8*)(sA + (size_t)(arow0 + mi * 16 + frow) * 64 + ks * 32 + fcol);
        #pragma unroll
        for (int ni = 0; ni < FN; ++ni)
            bfv[ni] = *(const bf16x8*)(sB + (size_t)(brow0 + ni * 16 + frow) * 64 + ks * 32 + fcol);
        #pragma unroll
        for (int mi = 0; mi < FM; ++mi)
            #pragma unroll
            for (int ni = 0; ni < FN; ++ni)
                acc[mi][ni] = __builtin_amdgcn_mfma_f32_16x16x32_bf16(
                    af[mi], bfv[ni], acc[mi][ni], 0, 0, 0);
    }
}

// MODE 2: if src[m]==atom: HID = bf16(gelu(acc + bias[atom*H_+n]))
// MODE 3: if dst[m]==atom: out[(b*SEQ+nn)*D_+n] = (acc + bias[atom*D_+n])*wgt[m]
template <int MODE, int BMc, int BNc, int WM, int WN>
__global__ __launch_bounds__(WM * WN * 64, 2)
void gemm2p(const ushort_t* __restrict__ A,
            const ushort_t* __restrict__ Bm,
            int N, int K, int grid_n,
            const float* __restrict__ bias,
            float* __restrict__ outF,
            ushort_t* __restrict__ outB,
            const int* __restrict__ selIdx,
            const float* __restrict__ wgt) {
    constexpr int NT = WM * WN * 64;
    constexpr int FM = BMc / WM / 16;
    constexpr int FN = BNc / WN / 16;

    __shared__ __align__(16) ushort_t A0[BMc * 64], A1[BMc * 64];
    __shared__ __align__(16) ushort_t B0[BNc * 64], B1[BNc * 64];

    const int nwg = gridDim.x;
    int bid = blockIdx.x;
    int q = nwg >> 3, r = nwg & 7;
    int xcd = bid & 7, slot = bid >> 3;
    int wg = (xcd < r ? xcd * (q + 1) : r * (q + 1) + (xcd - r) * q) + slot;
    int tile_m = wg / grid_n;
    int tile_n = wg - tile_m * grid_n;
    const int atom = blockIdx.z;

    const ushort_t* Ab = A  + (size_t)tile_m * BMc * K;
    const ushort_t* Bb = Bm + ((size_t)atom * N + (size_t)tile_n * BNc) * K;

    const int tid  = threadIdx.x;
    const int lane = tid & 63;
    const int wave = tid >> 6;
    const int arow0 = (wave / WN) * (BMc / WM);
    const int brow0 = (wave % WN) * (BNc / WN);

    f32x4 acc[FM][FN];
    #pragma unroll
    for (int i = 0; i < FM; i++)
        #pragma unroll
        for (int j = 0; j < FN; j++)
            acc[i][j] = (f32x4){0.f, 0.f, 0.f, 0.f};

    const int nkt = K >> 6;

    stage64<BMc, NT>(Ab, K, 0, A0, tid);
    stage64<BNc, NT>(Bb, K, 0, B0, tid);
    asm volatile("s_waitcnt vmcnt(0)" ::: "memory");
    __syncthreads();

    for (int t = 0; t < nkt; t += 2) {
        stage64<BMc, NT>(Ab, K, (t + 1) << 6, A1, tid);
        stage64<BNc, NT>(Bb, K, (t + 1) << 6, B1, tid);
        compute64c<FM, FN>(A0, B0, arow0, brow0, lane, acc);
        asm volatile("s_waitcnt vmcnt(0)" ::: "memory");
        __syncthreads();
        if (t + 2 < nkt) {
            stage64<BMc, NT>(Ab, K, (t + 2) << 6, A0, tid);
            stage64<BNc, NT>(Bb, K, (t + 2) << 6, B0, tid);
        }
        compute64c<FM, FN>(A1, B1, arow0, brow0, lane, acc);
        asm volatile("s_waitcnt vmcnt(0)" ::: "memory");
        __syncthreads();
    }

    const int frow = lane & 15;
    const int fq   = lane >> 4;
    #pragma unroll
    for (int mi = 0; mi < FM; mi++) {
        #pragma unroll
        for (int ni = 0; ni < FN; ni++) {
            int n = tile_n * BNc + brow0 + ni * 16 + frow;
            float bn;
            if constexpr (MODE == 2) bn = bias[atom * H_ + n];
            else                     bn = bias[atom * D_ + n];
            #pragma unroll
            for (int rr = 0; rr < 4; rr++) {
                int m = tile_m * BMc + arow0 + mi * 16 + fq * 4 + rr;
                float v = acc[mi][ni][rr];
                if constexpr (MODE == 2) {
                    if (selIdx[m] == atom)
                        outB[(size_t)m * N + n] = f2bf(gelu_fast(v + bn));
                } else { // MODE 3
                    if (selIdx[m] == atom) {
                        int b = m / NCLS, nn = m - b * NCLS;
                        outF[(size_t)(b * SEQ + nn) * D_ + n] = (v + bn) * wgt[m];
                    }
                }
            }
        }
    }
}

// ---------------------------------------------------------------------------
// Launch
// ---------------------------------------------------------------------------
extern "C" void kernel_launch(void* const* d_in, const int* in_sizes, int n_in,
                              void* d_out, int out_size, void* d_ws, size_t ws_size,
                              hipStream_t stream) {
    const float* x   = (const float*)d_in[0];
    const float* w1  = (const float*)d_in[1];
    const float* b1  = (const float*)d_in[2];
    const float* w2  = (const float*)d_in[3];
    const float* b2  = (const float*)d_in[4];
    const float* gd  = (const float*)d_in[5];
    const float* aiw = (const float*)d_in[6];
    const float* aib = (const float*)d_in[7];
    const float* aow = (const float*)d_in[8];
    const float* aob = (const float*)d_in[9];
    float* out = (float*)d_out;

    char* ws = (char*)d_ws;
    ushort_t* Xp   = (ushort_t*)ws; ws += (size_t)NPATCH * D_ * 2;
    ushort_t* W1b  = (ushort_t*)ws; ws += (size_t)H_ * D_ * 2;
    ushort_t* W2b  = (ushort_t*)ws; ws += (size_t)D_ * H_ * 2;
    ushort_t* H1   = (ushort_t*)ws; ws += (size_t)NPATCH * H_ * 2;
    ushort_t* CLSb = (ushort_t*)ws; ws += (size_t)NPAIR * D_ * 2;
    ushort_t* AIWb = (ushort_t*)ws; ws += (size_t)NATOMS * H_ * D_ * 2;
    ushort_t* AOWb = (ushort_t*)ws; ws += (size_t)NATOMS * D_ * H_ * 2;
    ushort_t* HID  = (ushort_t*)ws; ws += (size_t)NPAIR * H_ * 2;
    int*   SRC = (int*)ws;   ws += NPAIR * 4;
    int*   DST = (int*)ws;   ws += NPAIR * 4;
    float* WGT = (float*)ws; ws += NPAIR * 4;

    // prep: all conversions + x split + gate, one launch
    prep_kernel<<<PREP_NB, 256, 0, stream>>>(w1, W1b, w2, W2b, aiw, AIWb, aow, AOWb,
                                             x, Xp, CLSb, gd, SRC, DST, WGT);

    // patch MLP: r9-proven config for both GEMMs
    // (128x128 / BK=64 / 8 waves / 64KB LDS -> 2 blk/CU, counted VMW(4))
    gemm2s<0, 128, 128, 2, 4, 4><<<dim3(2352, 1, 1), 512, 0, stream>>>(
        Xp, W1b, H_, D_, 98, 24, b1, nullptr, H1);
    gemm2s<1, 128, 128, 2, 4, 4><<<dim3(588, 1, 1), 512, 0, stream>>>(
        H1, W2b, D_, H_, 98, 6, b2, out, nullptr);

    // cls path: dense all-atom GEMMs from pre-converted bf16 (r9-r13 proven)
    gemm2p<2, 64, 128, 1, 2><<<dim3(NPAIR / 64 * (H_ / 128), 1, NATOMS), 128, 0, stream>>>(
        CLSb, AIWb, H_, D_, H_ / 128, aib, nullptr, HID, SRC, nullptr);
    gemm2p<3, 64, 128, 1, 2><<<dim3(NPAIR / 64 * (D_ / 128), 1, NATOMS), 128, 0, stream>>>(
        HID, AOWb, D_, H_, D_ / 128, aob, out, nullptr, DST, WGT);
}

// Round 16
// 224.197 us; speedup vs baseline: 1.5250x; 1.3058x over previous
//
#include <hip/hip_runtime.h>
#include <hip/hip_bf16.h>
#include <stdint.h>

// ---------------------------------------------------------------------------
// Problem constants
// ---------------------------------------------------------------------------
#define NCLS   6
#define NATOMS 5
#define B_     64
#define P_     196
#define D_     768
#define H_     3072
#define SEQ    (NCLS + P_)        // 202
#define NPATCH (B_ * P_)          // 12544
#define NPAIR  (B_ * NCLS)        // 384

typedef unsigned short ushort_t;
typedef __attribute__((ext_vector_type(8))) short  bf16x8;
typedef __attribute__((ext_vector_type(4))) float  f32x4;

// ---------------------------------------------------------------------------
// Helpers
// ---------------------------------------------------------------------------
// fast tanh-form GELU (max abs err ~1e-3; threshold budget 3.98e-2)
__device__ __forceinline__ float gelu_fast(float x) {
    float x2 = x * x;
    float y  = x * (1.59576912f + 0.07135482f * x2);
    float e  = __expf(y);
    return x * e / (e + 1.0f);
}

__device__ __forceinline__ ushort_t f2bf(float f) {
    uint32_t u = __builtin_bit_cast(uint32_t, f);
    u = (u + 0x7fffu + ((u >> 16) & 1u)) >> 16;
    return (ushort_t)u;
}

__device__ __forceinline__ void gload16(const ushort_t* g, ushort_t* l) {
    __builtin_amdgcn_global_load_lds(
        (const __attribute__((address_space(1))) uint32_t*)g,
        (__attribute__((address_space(3))) uint32_t*)l,
        16, 0, 0);
}

// ---------------------------------------------------------------------------
// prep kernel: all fp32->bf16 conversions (w1,w2,aiw,aow) + x split + gate,
// ONE launch.  (r14 lesson: cls GEMMs MUST consume pre-converted bf16.)
// ---------------------------------------------------------------------------
#define CVT_B1   (H_ * D_ / 1024)                     // w1:   2304
#define CVT_B2   (CVT_B1 + D_ * H_ / 1024)            // +w2:  4608
#define CVT_B3   (CVT_B2 + NATOMS * H_ * D_ / 1024)   // +aiw: 16128
#define CVT_B4   (CVT_B3 + NATOMS * D_ * H_ / 1024)   // +aow: 27648
#define PREP_XE  (CVT_B4 + B_ * SEQ * D_ / 1024)      // +x:   37344
#define PREP_NB  (PREP_XE + NPAIR / 4)                // +gate: 37440

__global__ void prep_kernel(const float* __restrict__ w1, ushort_t* __restrict__ o1,
                            const float* __restrict__ w2, ushort_t* __restrict__ o2,
                            const float* __restrict__ aiw, ushort_t* __restrict__ o3,
                            const float* __restrict__ aow, ushort_t* __restrict__ o4,
                            const float* __restrict__ x, ushort_t* __restrict__ xp,
                            ushort_t* __restrict__ cls,
                            const float* __restrict__ gd,
                            int* __restrict__ srcA, int* __restrict__ dstA,
                            float* __restrict__ wgtA) {
    int bid = blockIdx.x;
    if (bid < CVT_B4) {
        const float* src; ushort_t* dst; int i;
        if (bid < CVT_B1)      { src = w1;  dst = o1; i = bid * 1024; }
        else if (bid < CVT_B2) { src = w2;  dst = o2; i = (bid - CVT_B1) * 1024; }
        else if (bid < CVT_B3) { src = aiw; dst = o3; i = (bid - CVT_B2) * 1024; }
        else                   { src = aow; dst = o4; i = (bid - CVT_B3) * 1024; }
        i += threadIdx.x * 4;
        float4 v = *(const float4*)(src + i);
        ushort4 o;
        o.x = f2bf(v.x); o.y = f2bf(v.y); o.z = f2bf(v.z); o.w = f2bf(v.w);
        *(ushort4*)(dst + i) = o;
    } else if (bid < PREP_XE) {
        int i = (bid - CVT_B4) * 1024 + threadIdx.x * 4;
        int row = i / D_;
        int col = i - row * D_;
        int b = row / SEQ, s = row - b * SEQ;
        float4 v = *(const float4*)(x + i);
        ushort4 o;
        o.x = f2bf(v.x); o.y = f2bf(v.y); o.z = f2bf(v.z); o.w = f2bf(v.w);
        if (s < NCLS) {
            *(ushort4*)(cls + (size_t)(b * NCLS + s) * D_ + col) = o;
        } else {
            *(ushort4*)(xp + (size_t)(b * P_ + (s - NCLS)) * D_ + col) = o;
        }
    } else {
        // gate: one wave per (b, n) pair
        int r = (bid - PREP_XE) * 4 + (threadIdx.x >> 6);
        int lane = threadIdx.x & 63;
        int b = r / NCLS, n = r - b * NCLS;
        const float* xr = x + (size_t)(b * SEQ + n) * D_;
        const float* g  = gd + (size_t)n * D_;
        float s = 0.f;
        for (int k = lane; k < D_; k += 64) s += xr[k] * g[k];
        #pragma unroll
        for (int off = 32; off > 0; off >>= 1) s += __shfl_down(s, off, 64);
        if (lane == 0) {
            float logit = s;
            bool left = (logit >= 0.f);
            float p = 1.f / (1.f + expf(-logit));
            float w = left ? p : (1.f - p);
            const int LK[NCLS] = {3, 4, 8, 9, 13, 14};
            const int RK[NCLS] = {15, 20, 16, 21, 17, 22};
            int key = left ? LK[n] : RK[n];
            srcA[r] = key / NATOMS;
            dstA[r] = key % NATOMS;
            wgtA[r] = w;
        }
    }
}

// ===========================================================================
// Shared GEMM building blocks
// ===========================================================================
// stage a [ROWS x 32] bf16 tile; inverse-swizzled global source, linear dest.
template <int ROWS, int NT>
__device__ __forceinline__ void stage_t32(const ushort_t* __restrict__ gpanel, int K,
                                          int kbase, ushort_t* lds, int tid) {
    constexpr int LOADS = ROWS * 4 / NT;
    static_assert(LOADS * NT == ROWS * 4, "stage divisibility");
    #pragma unroll
    for (int l = 0; l < LOADS; ++l) {
        int c = l * NT + tid;
        int row = c >> 2;
        int col = ((c & 3) ^ ((row >> 1) & 3)) << 3;
        gload16(gpanel + (size_t)row * K + kbase + col, lds + ((size_t)c << 3));
    }
}

#define BAR     asm volatile("s_barrier" ::: "memory")
#define VMW(N)  asm volatile("s_waitcnt vmcnt(" #N ")" ::: "memory")
#define VMW_C(VAL) do { \
    if constexpr ((VAL) == 4) { VMW(4); } else { VMW(8); } } while (0)

// ===========================================================================
// gemm2s_body: r9-proven BK=64 2-phase counted-vmcnt GEMM (patch MLP).
// 128x128 tile, 8 waves (2M x 4N), 64 KB LDS -> 2 blk/CU, VMW(4), L2
// cohorts 7m x 3n, swizzle slot^=(row>>1)&3 (0 bank conflicts).
// 105us @ 12544x3072x768 — AT the documented 2-phase structural ceiling
// (m230/m233: 607-682 TF at 4096^3; we get 564 TF at K=768).
// ===========================================================================
#define STAGE64T(T, DB) \
    stage_t32<BM, NT>(Ab, K, ((T) << 6),      &LA[DB][0][0], tid); \
    stage_t32<BN, NT>(Bb, K, ((T) << 6),      &LB[DB][0][0], tid); \
    stage_t32<BM, NT>(Ab, K, ((T) << 6) + 32, &LA[DB][1][0], tid); \
    stage_t32<BN, NT>(Bb, K, ((T) << 6) + 32, &LB[DB][1][0], tid);

#define COMPUTE64(DB) do { \
    __builtin_amdgcn_s_setprio(1); \
    _Pragma("unroll") \
    for (int ks = 0; ks < 2; ++ks) { \
        bf16x8 bfr[FN]; \
        _Pragma("unroll") \
        for (int f = 0; f < FN; ++f) \
            bfr[f] = *(const bf16x8*)(&LB[DB][ks][bbase + f * 512]); \
        _Pragma("unroll") \
        for (int mh = 0; mh < 2; ++mh) { \
            bf16x8 afr[FMH]; \
            _Pragma("unroll") \
            for (int f = 0; f < FMH; ++f) \
                afr[f] = *(const bf16x8*)(&LA[DB][ks][abase + mh * MH_OFF + f * 512]); \
            _Pragma("unroll") \
            for (int mi = 0; mi < FMH; ++mi) \
                _Pragma("unroll") \
                for (int ni = 0; ni < FN; ++ni) \
                    acc[mh * FMH + mi][ni] = __builtin_amdgcn_mfma_f32_16x16x32_bf16( \
                        afr[mi], bfr[ni], acc[mh * FMH + mi][ni], 0, 0, 0); \
        } \
    } \
    __builtin_amdgcn_s_setprio(0); \
    __builtin_amdgcn_sched_barrier(0); \
} while (0)

// MODE 0: H1 = bf16(gelu(acc + bias[n]))          (patch layer 1)
// MODE 1: out[(b*SEQ+NCLS+p)*D_+n] = acc+bias[n]  (patch layer 2)
template <int MODE, int BM, int BN, int WM, int WN>
__device__ __forceinline__ void gemm2s_body(char* SMEMc, int bid, int nwg,
        const ushort_t* __restrict__ A, const ushort_t* __restrict__ Bm,
        int N, int K, int grid_m, int grid_n,
        const float* __restrict__ bias,
        float* __restrict__ outF, ushort_t* __restrict__ outB) {
    constexpr int NT   = WM * WN * 64;
    constexpr int FMH  = BM / (32 * WM);
    constexpr int FN   = BN / (16 * WN);
    constexpr int MH_OFF = (BM / WM / 2) * 32;
    constexpr int VMWN = 8 * (BM + BN) / NT;

    typedef ushort_t lat[2][2][BM * 32];
    typedef ushort_t lbt[2][2][BN * 32];
    lat& LA = *(lat*)SMEMc;
    lbt& LB = *(lbt*)(SMEMc + sizeof(lat));

    // bijective XCD-chunk swizzle (m204) + L2 cohort decode (7m x 3n)
    int q = nwg >> 3, r = nwg & 7;
    int xcd = bid & 7, slot = bid >> 3;
    int wg = (xcd < r ? xcd * (q + 1) : r * (q + 1) + (xcd - r) * q) + slot;
    int per_col = (grid_m / 7) * 21;
    int gn = wg / per_col;  int r1 = wg - gn * per_col;
    int gm = r1 / 21;       int ii = r1 - gm * 21;
    int tile_m = gm * 7 + ii / 3;
    int tile_n = gn * 3 + (ii - (ii / 3) * 3);

    const ushort_t* Ab = A  + (size_t)tile_m * BM * K;
    const ushort_t* Bb = Bm + (size_t)tile_n * BN * K;

    const int tid  = threadIdx.x;
    const int lane = tid & 63;
    const int wave = tid >> 6;
    const int wr = wave / WN;
    const int wc = wave % WN;

    const int frow = lane & 15;
    const int fsl  = lane >> 4;
    const int rbase = frow * 32 + ((fsl ^ ((frow >> 1) & 3)) << 3);
    const int abase = wr * ((BM / WM) * 32) + rbase;
    const int bbase = wc * ((BN / WN) * 32) + rbase;

    f32x4 acc[2 * FMH][FN];
    #pragma unroll
    for (int i = 0; i < 2 * FMH; i++)
        #pragma unroll
        for (int j = 0; j < FN; j++)
            acc[i][j] = (f32x4){0.f, 0.f, 0.f, 0.f};

    const int nkt = K >> 6;

    STAGE64T(0, 0)
    for (int tb = 0; tb < (nkt >> 1) - 1; ++tb) {
        STAGE64T(2 * tb + 1, 1)
        VMW_C(VMWN); BAR;
        COMPUTE64(0);
        BAR;
        STAGE64T(2 * tb + 2, 0)
        VMW_C(VMWN); BAR;
        COMPUTE64(1);
        BAR;
    }
    STAGE64T(nkt - 1, 1)
    VMW_C(VMWN); BAR;
    COMPUTE64(0);
    BAR;
    VMW(0); BAR;
    COMPUTE64(1);

    // epilogue: C/D layout col = lane&15, row = (lane>>4)*4 + reg
    const int fq = lane >> 4;
    #pragma unroll
    for (int mi = 0; mi < 2 * FMH; mi++) {
        #pragma unroll
        for (int ni = 0; ni < FN; ni++) {
            int n = tile_n * BN + wc * (BN / WN) + ni * 16 + frow;
            float bn = bias[n];
            #pragma unroll
            for (int rr = 0; rr < 4; rr++) {
                int m = tile_m * BM + wr * (BM / WM) + mi * 16 + fq * 4 + rr;
                float v = acc[mi][ni][rr];
                if constexpr (MODE == 0) {
                    outB[(size_t)m * N + n] = f2bf(gelu_fast(v + bn));
                } else {
                    int b = m / P_, p = m - b * P_;
                    outF[(size_t)(b * SEQ + NCLS + p) * D_ + n] = v + bn;
                }
            }
        }
    }
}

// ---------------------------------------------------------------------------
// cls_body: 2-phase double-buffered cls GEMM (bf16 inputs, vmcnt(0) drains;
// latency-regime).  512-thread variant (8 waves, 2M x 4N) so it can ride the
// patch-GEMM launches' dispatch tails (r15->r16 merge).
// ---------------------------------------------------------------------------
template <int ROWS, int NT>
__device__ __forceinline__ void stage64(const ushort_t* __restrict__ gbase, int K,
                                        int k0, ushort_t* lds, int tid) {
    constexpr int LOADS = ROWS * 64 * 2 / (NT * 16);
    #pragma unroll
    for (int l = 0; l < LOADS; ++l) {
        int c = l * NT + tid;
        gload16(gbase + (size_t)(c >> 3) * K + k0 + ((c & 7) << 3),
                lds + (size_t)c * 8);
    }
}

template <int FM, int FN>
__device__ __forceinline__ void compute64c(const ushort_t* sA, const ushort_t* sB,
                                           int arow0, int brow0, int lane,
                                           f32x4 (&acc)[FM][FN]) {
    const int frow = lane & 15;
    const int fcol = (lane >> 4) * 8;
    #pragma unroll
    for (int ks = 0; ks < 2; ++ks) {
        bf16x8 af[FM], bfv[FN];
        #pragma unroll
        for (int mi = 0; mi < FM; ++mi)
            af[mi] = *(const bf16x8*)(sA + (size_t)(arow0 + mi * 16 + frow) * 64 + ks * 32 + fcol);
        #pragma unroll
        for (int ni = 0; ni < FN; ++ni)
            bfv[ni] = *(const bf16x8*)(sB + (size_t)(brow0 + ni * 16 + frow) * 64 + ks * 32 + fcol);
        #pragma unroll
        for (int mi = 0; mi < FM; ++mi)
            #pragma unroll
            for (int ni = 0; ni < FN; ++ni)
                acc[mi][ni] = __builtin_amdgcn_mfma_f32_16x16x32_bf16(
                    af[mi], bfv[ni], acc[mi][ni], 0, 0, 0);
    }
}

// MODE 2: if src[m]==atom: HID = bf16(gelu(acc + bias[atom*H_+n]))
// MODE 3: if dst[m]==atom: out[(b*SEQ+nn)*D_+n] = (acc + bias[atom*D_+n])*wgt[m]
template <int MODE, int BMc, int BNc, int WM, int WN>
__device__ __forceinline__ void cls_body(char* SMEMc, int tile_m, int tile_n, int atom,
        const ushort_t* __restrict__ A, const ushort_t* __restrict__ Bm,
        int N, int K, const float* __restrict__ bias,
        float* __restrict__ outF, ushort_t* __restrict__ outB,
        const int* __restrict__ selIdx, const float* __restrict__ wgt) {
    constexpr int NT = WM * WN * 64;     // 512
    constexpr int FM = BMc / WM / 16;    // 2
    constexpr int FN = BNc / WN / 16;    // 2

    ushort_t* A0 = (ushort_t*)SMEMc;
    ushort_t* A1 = A0 + BMc * 64;
    ushort_t* B0 = A1 + BMc * 64;
    ushort_t* B1 = B0 + BNc * 64;

    const ushort_t* Ab = A  + (size_t)tile_m * BMc * K;
    const ushort_t* Bb = Bm + ((size_t)atom * N + (size_t)tile_n * BNc) * K;

    const int tid  = threadIdx.x;
    const int lane = tid & 63;
    const int wave = tid >> 6;
    const int arow0 = (wave / WN) * (BMc / WM);
    const int brow0 = (wave % WN) * (BNc / WN);

    f32x4 acc[FM][FN];
    #pragma unroll
    for (int i = 0; i < FM; i++)
        #pragma unroll
        for (int j = 0; j < FN; j++)
            acc[i][j] = (f32x4){0.f, 0.f, 0.f, 0.f};

    const int nkt = K >> 6;

    stage64<BMc, NT>(Ab, K, 0, A0, tid);
    stage64<BNc, NT>(Bb, K, 0, B0, tid);
    asm volatile("s_waitcnt vmcnt(0)" ::: "memory");
    __syncthreads();

    for (int t = 0; t < nkt; t += 2) {
        stage64<BMc, NT>(Ab, K, (t + 1) << 6, A1, tid);
        stage64<BNc, NT>(Bb, K, (t + 1) << 6, B1, tid);
        compute64c<FM, FN>(A0, B0, arow0, brow0, lane, acc);
        asm volatile("s_waitcnt vmcnt(0)" ::: "memory");
        __syncthreads();
        if (t + 2 < nkt) {
            stage64<BMc, NT>(Ab, K, (t + 2) << 6, A0, tid);
            stage64<BNc, NT>(Bb, K, (t + 2) << 6, B0, tid);
        }
        compute64c<FM, FN>(A1, B1, arow0, brow0, lane, acc);
        asm volatile("s_waitcnt vmcnt(0)" ::: "memory");
        __syncthreads();
    }

    const int frow = lane & 15;
    const int fq   = lane >> 4;
    #pragma unroll
    for (int mi = 0; mi < FM; mi++) {
        #pragma unroll
        for (int ni = 0; ni < FN; ni++) {
            int n = tile_n * BNc + brow0 + ni * 16 + frow;
            float bn;
            if constexpr (MODE == 2) bn = bias[atom * H_ + n];
            else                     bn = bias[atom * D_ + n];
            #pragma unroll
            for (int rr = 0; rr < 4; rr++) {
                int m = tile_m * BMc + arow0 + mi * 16 + fq * 4 + rr;
                float v = acc[mi][ni][rr];
                if constexpr (MODE == 2) {
                    if (selIdx[m] == atom)
                        outB[(size_t)m * N + n] = f2bf(gelu_fast(v + bn));
                } else { // MODE 3
                    if (selIdx[m] == atom) {
                        int b = m / NCLS, nn = m - b * NCLS;
                        outF[(size_t)(b * SEQ + nn) * D_ + n] = (v + bn) * wgt[m];
                    }
                }
            }
        }
    }
}

// ===========================================================================
// Merged launches: cls blocks ride the patch GEMMs' dispatch tails.
// Kernel A = GEMM0 (2352 blocks) + cls-in (720 blocks: 6m x 24n x 5 atoms).
//   deps: both need only prep outputs.  GEMM0 writes H1; cls-in writes HID.
// Kernel B = GEMM1 (588 blocks) + cls-out (180 blocks: 6m x 6n x 5 atoms).
//   deps: GEMM1 needs H1 (A); cls-out needs HID (A).  Disjoint out rows.
// ===========================================================================
#define G0_NB  2352
#define CIN_NB 720
#define G1_NB  588
#define COUT_NB 180

__global__ __launch_bounds__(512, 4)
void kernelA(const ushort_t* __restrict__ Xp, const ushort_t* __restrict__ W1b,
             const float* __restrict__ b1, ushort_t* __restrict__ H1,
             const ushort_t* __restrict__ CLSb, const ushort_t* __restrict__ AIWb,
             const float* __restrict__ aib, ushort_t* __restrict__ HID,
             const int* __restrict__ SRC) {
    __shared__ __align__(16) char SMEM[65536];
    if (blockIdx.x < G0_NB) {
        gemm2s_body<0, 128, 128, 2, 4>(SMEM, blockIdx.x, G0_NB,
                                       Xp, W1b, H_, D_, 98, 24, b1, nullptr, H1);
    } else {
        int c = blockIdx.x - G0_NB;
        int atom = c / 144;  int r1 = c - atom * 144;
        cls_body<2, 64, 128, 2, 4>(SMEM, r1 / 24, r1 % 24, atom,
                                   CLSb, AIWb, H_, D_, aib, nullptr, HID, SRC, nullptr);
    }
}

__global__ __launch_bounds__(512, 4)
void kernelB(const ushort_t* __restrict__ H1, const ushort_t* __restrict__ W2b,
             const float* __restrict__ b2, float* __restrict__ out,
             const ushort_t* __restrict__ HID, const ushort_t* __restrict__ AOWb,
             const float* __restrict__ aob, const int* __restrict__ DST,
             const float* __restrict__ WGT) {
    __shared__ __align__(16) char SMEM[65536];
    if (blockIdx.x < G1_NB) {
        gemm2s_body<1, 128, 128, 2, 4>(SMEM, blockIdx.x, G1_NB,
                                       H1, W2b, D_, H_, 98, 6, b2, out, nullptr);
    } else {
        int c = blockIdx.x - G1_NB;
        int atom = c / 36;  int r1 = c - atom * 36;
        cls_body<3, 64, 128, 2, 4>(SMEM, r1 / 6, r1 % 6, atom,
                                   HID, AOWb, D_, H_, aob, out, nullptr, DST, WGT);
    }
}

// ---------------------------------------------------------------------------
// Launch
// ---------------------------------------------------------------------------
extern "C" void kernel_launch(void* const* d_in, const int* in_sizes, int n_in,
                              void* d_out, int out_size, void* d_ws, size_t ws_size,
                              hipStream_t stream) {
    const float* x   = (const float*)d_in[0];
    const float* w1  = (const float*)d_in[1];
    const float* b1  = (const float*)d_in[2];
    const float* w2  = (const float*)d_in[3];
    const float* b2  = (const float*)d_in[4];
    const float* gd  = (const float*)d_in[5];
    const float* aiw = (const float*)d_in[6];
    const float* aib = (const float*)d_in[7];
    const float* aow = (const float*)d_in[8];
    const float* aob = (const float*)d_in[9];
    float* out = (float*)d_out;

    char* ws = (char*)d_ws;
    ushort_t* Xp   = (ushort_t*)ws; ws += (size_t)NPATCH * D_ * 2;
    ushort_t* W1b  = (ushort_t*)ws; ws += (size_t)H_ * D_ * 2;
    ushort_t* W2b  = (ushort_t*)ws; ws += (size_t)D_ * H_ * 2;
    ushort_t* H1   = (ushort_t*)ws; ws += (size_t)NPATCH * H_ * 2;
    ushort_t* CLSb = (ushort_t*)ws; ws += (size_t)NPAIR * D_ * 2;
    ushort_t* AIWb = (ushort_t*)ws; ws += (size_t)NATOMS * H_ * D_ * 2;
    ushort_t* AOWb = (ushort_t*)ws; ws += (size_t)NATOMS * D_ * H_ * 2;
    ushort_t* HID  = (ushort_t*)ws; ws += (size_t)NPAIR * H_ * 2;
    int*   SRC = (int*)ws;   ws += NPAIR * 4;
    int*   DST = (int*)ws;   ws += NPAIR * 4;
    float* WGT = (float*)ws; ws += NPAIR * 4;

    // prep: all conversions + x split + gate, one launch
    prep_kernel<<<PREP_NB, 256, 0, stream>>>(w1, W1b, w2, W2b, aiw, AIWb, aow, AOWb,
                                             x, Xp, CLSb, gd, SRC, DST, WGT);

    // kernel A: GEMM0 + cls-in (tail-fill)
    kernelA<<<dim3(G0_NB + CIN_NB, 1, 1), 512, 0, stream>>>(
        Xp, W1b, b1, H1, CLSb, AIWb, aib, HID, SRC);

    // kernel B: GEMM1 + cls-out (tail-fill)
    kernelB<<<dim3(G1_NB + COUT_NB, 1, 1), 512, 0, stream>>>(
        H1, W2b, b2, out, HID, AOWb, aob, DST, WGT);
}